// Round 14
// baseline (244.137 us; speedup 1.0000x reference)
//
#include <hip/hip_runtime.h>

// ---------------------------------------------------------------------------
// 2-layer GraphSAGE (mean aggr), CSR-pull aggregation + bf16-MFMA GEMMs.
//   prep: x->bf16 + weight hi/lo split + COARSE (dst>>8) LDS histogram
//   ccscan: 1-block scan of 196 coarse counts -> cbase/gcur
//   msplit: block-local LDS sort by dst>>8, coalesced run flush -> staging
//   bsort: per-bucket fine hist -> offs[] + counting sort -> src_sorted
//   mean1 = mean_agg(x_bf)                      -> bf16   [M,128]
//   h     = relu(mean1@W1l^T + b1 + x_bf@W1r^T) -> bf16   [M,256]  (MFMA)
//   {p, out0} = h @ {W2l,W2r}^T (dual GEMM)  p->bf16, out0=h@W2r^T+b2 (fp32)
//   out  += mean_agg(p)
// Weights hi/lo bf16 split (2 MFMAs/product) — REQUIRED: single-bf16 weights
// measured absmax 6.3e-2 > 2.8e-2 (round 10); hi/lo gives 7.8e-3.
// Aggregation: dword-per-lane (lane owns 2 cols), 4x edge unroll — REQUIRED:
// the 2-edge/wave uint2 variant measured 4.35e-2 (rounds 10/12, unexplained).
// ws: ccount|cbase|gcur|offs | staging(uint2 E) | src_sorted[E]
//     | mean1_bf | p_bf | h_bf | wbuf(8xWN hi/lo) | x_bf   total ~74MB
// ---------------------------------------------------------------------------

typedef short bf16x8 __attribute__((ext_vector_type(8)));
typedef float f32x4  __attribute__((ext_vector_type(4)));

__device__ __forceinline__ unsigned f2bf(float f) {         // RNE fp32->bf16 bits
    unsigned u = __float_as_uint(f);
    return (u + 0x7FFFu + ((u >> 16) & 1u)) >> 16;
}
__device__ __forceinline__ unsigned pack2(float a, float b) {
    return f2bf(a) | (f2bf(b) << 16);
}
__device__ __forceinline__ float2 bfunpack(unsigned u) {    // (low, high) bf16 -> fp32
    return make_float2(__uint_as_float(u << 16), __uint_as_float(u & 0xffff0000u));
}

// exclusive scan of 256 ints in LDS (wave 0 only; caller syncs)
__device__ __forceinline__ void scan256(const int* __restrict__ h,
                                        int* __restrict__ out, int tid) {
    if (tid < 64) {
        const int i4 = tid * 4;
        const int v0 = h[i4], v1 = h[i4 + 1], v2 = h[i4 + 2], v3 = h[i4 + 3];
        const int t = v0 + v1 + v2 + v3;
        int x = t;
        #pragma unroll
        for (int dd = 1; dd < 64; dd <<= 1) {
            const int y = __shfl_up(x, dd, 64);
            if (tid >= dd) x += y;
        }
        const int ex = x - t;
        out[i4] = ex; out[i4 + 1] = ex + v0;
        out[i4 + 2] = ex + v0 + v1; out[i4 + 3] = ex + v0 + v1 + v2;
    }
}

// ----------------------------- fused prep ----------------------------------
// roles by blockIdx.x: [0,nbF) f2bf(x) | [nbF,nbF+nbW) wsplit | rest: coarse count
__global__ __launch_bounds__(256)
void prep_kernel(const float* __restrict__ x, short* __restrict__ x_bf, long nx,
                 const float* __restrict__ W0, const float* __restrict__ W1,
                 const float* __restrict__ W2, const float* __restrict__ W3,
                 short* __restrict__ wbuf, int wn,
                 const int* __restrict__ dst, int* __restrict__ ccount, int E,
                 int nbF, int nbW) {
    __shared__ int ch[256];
    const int bx = blockIdx.x, tid = threadIdx.x;
    if (bx < nbF) {
        const long i = ((long)bx * 256 + tid) * 8;
        if (i + 8 <= nx) {
            const float4 a = *(const float4*)(x + i);
            const float4 b = *(const float4*)(x + i + 4);
            *(uint4*)(x_bf + i) = make_uint4(pack2(a.x, a.y), pack2(a.z, a.w),
                                             pack2(b.x, b.y), pack2(b.z, b.w));
        }
    } else if (bx < nbF + nbW) {
        const int rel = bx - nbF;
        const int w = rel >> 7;                  // 128 blocks per weight
        const float* __restrict__ W = (w == 0) ? W0 : (w == 1) ? W1 : (w == 2) ? W2 : W3;
        short* hi = wbuf + (long)(2 * w) * wn;
        short* lo = hi + wn;
        const int i = (rel & 127) * 256 + tid;
        if (i < wn) {
            const float v = W[i];
            const unsigned h = f2bf(v);
            hi[i] = (short)h;
            lo[i] = (short)f2bf(v - __uint_as_float(h << 16));
        }
    } else {
        const int hb = bx - nbF - nbW;
        ch[tid] = 0;
        __syncthreads();
        const long base = (long)hb * 8192;
        #pragma unroll
        for (int k = 0; k < 32; ++k) {
            const long i = base + (long)k * 256 + tid;
            if (i < E) atomicAdd(&ch[dst[i] >> 8], 1);
        }
        __syncthreads();
        const int c = ch[tid];
        if (c) atomicAdd(&ccount[tid], c);
    }
}

// ----------------------------- coarse scan (1 block, 64 thr) ---------------
__global__ void ccscan_kernel(const int* __restrict__ ccount, int* __restrict__ cbase,
                              int* __restrict__ gcur, int NBK, int E) {
    const int lane = threadIdx.x;   // 64 threads
    int v[4]; int t = 0;
    #pragma unroll
    for (int i = 0; i < 4; ++i) {
        const int b = lane * 4 + i;
        v[i] = (b < NBK) ? ccount[b] : 0;
        t += v[i];
    }
    int x = t;
    #pragma unroll
    for (int d = 1; d < 64; d <<= 1) {
        const int y = __shfl_up(x, d, 64);
        if (lane >= d) x += y;
    }
    int ex = x - t;   // exclusive prefix of this thread's chunk
    #pragma unroll
    for (int i = 0; i < 4; ++i) {
        const int b = lane * 4 + i;
        if (b < NBK) { cbase[b] = ex; gcur[b] = ex; }
        ex += v[i];
    }
    if (lane == 63) cbase[NBK] = E;
}

// ----------------------------- coarse multisplit ---------------------------
__global__ __launch_bounds__(1024)
void msplit_kernel(const int* __restrict__ src, const int* __restrict__ dst,
                   int* __restrict__ gcur, uint2* __restrict__ staging, int E) {
    __shared__ int hist[256], scanex[256], gb[256];
    __shared__ uint2 pairs[4096];
    const int tid = threadIdx.x;
    const long base = (long)blockIdx.x * 4096;
    const int cnt = min(4096, (int)(E - base));
    if (tid < 256) hist[tid] = 0;
    __syncthreads();
    int d[4], s[4];
    #pragma unroll
    for (int k = 0; k < 4; ++k) {
        const int i = tid + k * 1024;
        if (i < cnt) {
            d[k] = dst[base + i]; s[k] = src[base + i];
            atomicAdd(&hist[d[k] >> 8], 1);
        }
    }
    __syncthreads();
    scan256(hist, scanex, tid);
    __syncthreads();
    if (tid < 256) {
        const int c = hist[tid];
        gb[tid] = c ? atomicAdd(&gcur[tid], c) : 0;
        hist[tid] = scanex[tid];                 // becomes LDS cursor
    }
    __syncthreads();
    #pragma unroll
    for (int k = 0; k < 4; ++k) {
        const int i = tid + k * 1024;
        if (i < cnt) {
            const int b = d[k] >> 8;
            const int pos = atomicAdd(&hist[b], 1);
            pairs[pos] = make_uint2((unsigned)s[k], (unsigned)d[k]);
        }
    }
    __syncthreads();
    #pragma unroll
    for (int k = 0; k < 4; ++k) {
        const int i = tid + k * 1024;
        if (i < cnt) {
            const uint2 pr = pairs[i];
            const int b = (int)(pr.y >> 8);
            staging[gb[b] + (i - scanex[b])] = pr;    // bucket-contiguous runs
        }
    }
}

// ----------------------------- per-bucket sort + offs ----------------------
__global__ __launch_bounds__(1024)
void bsort_kernel(const uint2* __restrict__ staging, const int* __restrict__ cbase,
                  int* __restrict__ offs, int* __restrict__ src_sorted,
                  int M, int NBK) {
    const int b = blockIdx.x;
    const int n0 = b * 256;
    const int s0 = cbase[b], s1 = cbase[b + 1];
    const int cnt = s1 - s0;
    const int tid = threadIdx.x;
    __shared__ int hist[256], base2[256];
    __shared__ int lsrc[8192];
    if (tid < 256) hist[tid] = 0;
    __syncthreads();
    for (int i = tid; i < cnt; i += 1024)
        atomicAdd(&hist[staging[s0 + i].y & 255], 1);
    __syncthreads();
    scan256(hist, base2, tid);
    __syncthreads();
    if (tid < 256) {
        const int node = n0 + tid;
        if (node < M) offs[node] = s0 + base2[tid];
        hist[tid] = base2[tid];                  // becomes cursor
    }
    if (b == NBK - 1 && tid == 0) offs[M] = s1;
    __syncthreads();
    if (cnt <= 8192) {
        for (int i = tid; i < cnt; i += 1024) {
            const uint2 pr = staging[s0 + i];
            const int pos = atomicAdd(&hist[pr.y & 255], 1);
            lsrc[pos] = (int)pr.x;
        }
        __syncthreads();
        for (int i = tid; i < cnt; i += 1024)
            src_sorted[s0 + i] = lsrc[i];        // fully coalesced
    } else {                                     // rare huge-bucket fallback
        for (int i = tid; i < cnt; i += 1024) {
            const uint2 pr = staging[s0 + i];
            const int pos = atomicAdd(&hist[pr.y & 255], 1);
            src_sorted[s0 + pos] = (int)pr.x;
        }
    }
}

// ----------------------------- aggregation ---------------------------------
template<int F, bool BF16_OUT, bool ADD>
__global__ __launch_bounds__(256)
void agg_mean_kernel(const short* __restrict__ feat, const int* __restrict__ src_sorted,
                     const int* __restrict__ offs, void* __restrict__ outv, int M) {
    const int node = blockIdx.x * 4 + (threadIdx.x >> 6);
    if (node >= M) return;
    const int lane = threadIdx.x & 63;
    const int start = offs[node], end = offs[node + 1];
    const unsigned* fb = (const unsigned*)feat;       // row stride F/2 dwords
    float2 acc = make_float2(0.f, 0.f);
    for (int e0 = start; e0 < end; e0 += 64) {
        const int n = min(64, end - e0);
        const int sv = (e0 + lane < end) ? src_sorted[e0 + lane] : 0;
        int j = 0;
        for (; j + 4 <= n; j += 4) {
            const int s0 = __shfl(sv, j, 64),     s1 = __shfl(sv, j + 1, 64);
            const int s2 = __shfl(sv, j + 2, 64), s3 = __shfl(sv, j + 3, 64);
            const unsigned u0 = fb[(long)s0 * (F / 2) + lane];
            const unsigned u1 = fb[(long)s1 * (F / 2) + lane];
            const unsigned u2 = fb[(long)s2 * (F / 2) + lane];
            const unsigned u3 = fb[(long)s3 * (F / 2) + lane];
            const float2 v0 = bfunpack(u0), v1 = bfunpack(u1);
            const float2 v2 = bfunpack(u2), v3 = bfunpack(u3);
            acc.x += (v0.x + v1.x) + (v2.x + v3.x);
            acc.y += (v0.y + v1.y) + (v2.y + v3.y);
        }
        for (; j < n; ++j) {
            const int s = __shfl(sv, j, 64);
            const float2 v = bfunpack(fb[(long)s * (F / 2) + lane]);
            acc.x += v.x; acc.y += v.y;
        }
    }
    const float inv = (end > start) ? 1.0f / (float)(end - start) : 0.f;
    acc.x *= inv; acc.y *= inv;
    if (BF16_OUT) {
        ((unsigned*)outv)[(long)node * (F / 2) + lane] = pack2(acc.x, acc.y);
    } else if (ADD) {
        float2* op = reinterpret_cast<float2*>((float*)outv + (long)node * F + lane * 2);
        const float2 cur = *op;
        *op = make_float2(cur.x + acc.x, cur.y + acc.y);
    } else {
        *reinterpret_cast<float2*>((float*)outv + (long)node * F + lane * 2) = acc;
    }
}

// ----------------------------- MFMA GEMM (layer 1) -------------------------
template<int KP>
__device__ __forceinline__ void gemm_phase(const short* __restrict__ A,
    const short* __restrict__ Whi, const short* __restrict__ Wlo,
    int M, int row0, int col0,
    short (*As)[40], short (*Bh)[40], short (*Bl)[40], f32x4 (&acc)[4][4])
{
    const int tid = threadIdx.x;
    const int lane = tid & 63;
    const int wr = (tid >> 7) & 1, wc = (tid >> 6) & 1;
    const int l15 = lane & 15, l4 = lane >> 4;
    const int sr = tid >> 1;
    const int sk = (tid & 1) * 16;
    const int gr = row0 + sr;

    for (int k0 = 0; k0 < KP; k0 += 32) {
        {
            const short* ap = A + (long)gr * KP + k0 + sk;
            uint4 v0 = make_uint4(0, 0, 0, 0), v1 = make_uint4(0, 0, 0, 0);
            if (gr < M) { v0 = *(const uint4*)ap; v1 = *(const uint4*)(ap + 8); }
            *(uint4*)&As[sr][sk]     = v0;
            *(uint4*)&As[sr][sk + 8] = v1;
        }
        {
            const short* bh = Whi + (long)(col0 + sr) * KP + k0 + sk;
            const short* bl = Wlo + (long)(col0 + sr) * KP + k0 + sk;
            *(uint4*)&Bh[sr][sk]     = *(const uint4*)bh;
            *(uint4*)&Bh[sr][sk + 8] = *(const uint4*)(bh + 8);
            *(uint4*)&Bl[sr][sk]     = *(const uint4*)bl;
            *(uint4*)&Bl[sr][sk + 8] = *(const uint4*)(bl + 8);
        }
        __syncthreads();
        bf16x8 bhf[4], blf[4];
        #pragma unroll
        for (int n = 0; n < 4; ++n) {
            const int br = wc * 64 + n * 16 + l15;
            bhf[n] = *(const bf16x8*)&Bh[br][l4 * 8];
            blf[n] = *(const bf16x8*)&Bl[br][l4 * 8];
        }
        #pragma unroll
        for (int m = 0; m < 4; ++m) {
            const bf16x8 af = *(const bf16x8*)&As[wr * 64 + m * 16 + l15][l4 * 8];
            #pragma unroll
            for (int n = 0; n < 4; ++n) {
                acc[m][n] = __builtin_amdgcn_mfma_f32_16x16x32_bf16(af, bhf[n], acc[m][n], 0, 0, 0);
                acc[m][n] = __builtin_amdgcn_mfma_f32_16x16x32_bf16(af, blf[n], acc[m][n], 0, 0, 0);
            }
        }
        __syncthreads();
    }
}

template<int K1, int K2, int NOUT, bool TWO_PHASE,
         bool RELU, bool HAS_BIAS, bool OUT_BF16>
__global__ __launch_bounds__(256)
void mfma_gemm(const short* __restrict__ A1, const short* __restrict__ A2,
               const short* __restrict__ B1hi, const short* __restrict__ B1lo,
               const short* __restrict__ B2hi, const short* __restrict__ B2lo,
               const float* __restrict__ bias, void* __restrict__ Cv, int M)
{
    __shared__ __align__(16) short As[128][40];
    __shared__ __align__(16) short Bh[128][40];
    __shared__ __align__(16) short Bl[128][40];
    const int row0 = blockIdx.x * 128, col0 = blockIdx.y * 128;
    f32x4 acc[4][4] = {};

    if constexpr (TWO_PHASE)
        gemm_phase<K1>(A1, B1hi, B1lo, M, row0, col0, As, Bh, Bl, acc);
    gemm_phase<K2>(A2, B2hi, B2lo, M, row0, col0, As, Bh, Bl, acc);

    const int tid = threadIdx.x, lane = tid & 63;
    const int wr = (tid >> 7) & 1, wc = (tid >> 6) & 1;
    const int l15 = lane & 15, l4 = lane >> 4;
    float bv[4];
    #pragma unroll
    for (int n = 0; n < 4; ++n)
        bv[n] = HAS_BIAS ? bias[col0 + wc * 64 + n * 16 + l15] : 0.f;
    #pragma unroll
    for (int m = 0; m < 4; ++m) {
        #pragma unroll
        for (int i = 0; i < 4; ++i) {
            const int r = row0 + wr * 64 + m * 16 + l4 * 4 + i;
            if (r < M) {
                #pragma unroll
                for (int n = 0; n < 4; ++n) {
                    const int c = col0 + wc * 64 + n * 16 + l15;
                    float v = acc[m][n][i] + bv[n];
                    if (RELU) v = fmaxf(v, 0.f);
                    if (OUT_BF16) ((short*)Cv)[(long)r * NOUT + c] = (short)f2bf(v);
                    else          ((float*)Cv)[(long)r * NOUT + c] = v;
                }
            }
        }
    }
}

// ----------------------------- dual MFMA GEMM (layer 2) --------------------
template<int K, int NOUT>
__global__ __launch_bounds__(256)
void mfma_gemm_dual(const short* __restrict__ A,
                    const short* __restrict__ Wahi, const short* __restrict__ Walo,
                    const short* __restrict__ Wbhi, const short* __restrict__ Wblo,
                    const float* __restrict__ bias, short* __restrict__ Ca,
                    float* __restrict__ Cb, int M)
{
    __shared__ __align__(16) short As[128][40];
    __shared__ __align__(16) short Bh[2][128][40];
    __shared__ __align__(16) short Bl[2][128][40];
    const int row0 = blockIdx.x * 128;
    f32x4 acc[2][4][4] = {};

    const int tid = threadIdx.x, lane = tid & 63;
    const int wr = (tid >> 7) & 1, wc = (tid >> 6) & 1;
    const int l15 = lane & 15, l4 = lane >> 4;
    const int sr = tid >> 1;
    const int sk = (tid & 1) * 16;
    const int gr = row0 + sr;

    for (int k0 = 0; k0 < K; k0 += 32) {
        {
            const short* ap = A + (long)gr * K + k0 + sk;
            uint4 v0 = make_uint4(0, 0, 0, 0), v1 = make_uint4(0, 0, 0, 0);
            if (gr < M) { v0 = *(const uint4*)ap; v1 = *(const uint4*)(ap + 8); }
            *(uint4*)&As[sr][sk]     = v0;
            *(uint4*)&As[sr][sk + 8] = v1;
        }
        {
            const short* bh0 = Wahi + (long)sr * K + k0 + sk;
            const short* bl0 = Walo + (long)sr * K + k0 + sk;
            const short* bh1 = Wbhi + (long)sr * K + k0 + sk;
            const short* bl1 = Wblo + (long)sr * K + k0 + sk;
            *(uint4*)&Bh[0][sr][sk]     = *(const uint4*)bh0;
            *(uint4*)&Bh[0][sr][sk + 8] = *(const uint4*)(bh0 + 8);
            *(uint4*)&Bl[0][sr][sk]     = *(const uint4*)bl0;
            *(uint4*)&Bl[0][sr][sk + 8] = *(const uint4*)(bl0 + 8);
            *(uint4*)&Bh[1][sr][sk]     = *(const uint4*)bh1;
            *(uint4*)&Bh[1][sr][sk + 8] = *(const uint4*)(bh1 + 8);
            *(uint4*)&Bl[1][sr][sk]     = *(const uint4*)bl1;
            *(uint4*)&Bl[1][sr][sk + 8] = *(const uint4*)(bl1 + 8);
        }
        __syncthreads();
        bf16x8 af[4];
        #pragma unroll
        for (int m = 0; m < 4; ++m)
            af[m] = *(const bf16x8*)&As[wr * 64 + m * 16 + l15][l4 * 8];
        #pragma unroll
        for (int w = 0; w < 2; ++w) {
            #pragma unroll
            for (int n = 0; n < 4; ++n) {
                const int br = wc * 64 + n * 16 + l15;
                const bf16x8 bhf = *(const bf16x8*)&Bh[w][br][l4 * 8];
                const bf16x8 blf = *(const bf16x8*)&Bl[w][br][l4 * 8];
                #pragma unroll
                for (int m = 0; m < 4; ++m) {
                    acc[w][m][n] = __builtin_amdgcn_mfma_f32_16x16x32_bf16(af[m], bhf, acc[w][m][n], 0, 0, 0);
                    acc[w][m][n] = __builtin_amdgcn_mfma_f32_16x16x32_bf16(af[m], blf, acc[w][m][n], 0, 0, 0);
                }
            }
        }
        __syncthreads();
    }

    float bv[4];
    #pragma unroll
    for (int n = 0; n < 4; ++n)
        bv[n] = bias[wc * 64 + n * 16 + l15];
    #pragma unroll
    for (int m = 0; m < 4; ++m) {
        #pragma unroll
        for (int i = 0; i < 4; ++i) {
            const int r = row0 + wr * 64 + m * 16 + l4 * 4 + i;
            if (r < M) {
                #pragma unroll
                for (int n = 0; n < 4; ++n) {
                    const int c = wc * 64 + n * 16 + l15;
                    Ca[(long)r * NOUT + c] = (short)f2bf(acc[0][m][n][i]);
                    Cb[(long)r * NOUT + c] = acc[1][m][n][i] + bv[n];
                }
            }
        }
    }
}

// ----------------------------- launch --------------------------------------
extern "C" void kernel_launch(void* const* d_in, const int* in_sizes, int n_in,
                              void* d_out, int out_size, void* d_ws, size_t ws_size,
                              hipStream_t stream) {
    const float* x   = (const float*)d_in[0];
    const int*   ei  = (const int*)d_in[1];
    const float* W1l = (const float*)d_in[2];
    const float* b1  = (const float*)d_in[3];
    const float* W1r = (const float*)d_in[4];
    const float* W2l = (const float*)d_in[5];
    const float* b2  = (const float*)d_in[6];
    const float* W2r = (const float*)d_in[7];
    float* out = (float*)d_out;

    const int M = in_sizes[0] / 128;   // 50000
    const int E = in_sizes[1] / 2;     // 800000
    const int* src = ei;
    const int* dst = ei + E;

    const int NBK = (M + 255) / 256;               // 196 coarse buckets
    const int Mal = ((M + 1 + 63) / 64) * 64;

    int* ccount     = (int*)d_ws;                               // [256]
    int* cbase      = ccount + 256;                             // [NBK+1] (<=320)
    int* gcur       = cbase + 320;                              // [256]
    int* offs       = gcur + 256;                               // [M+1]
    uint2* staging  = (uint2*)(offs + Mal);                     // [E] 8B pairs
    int* src_sorted = (int*)(staging + E);                      // [E]
    short* mean1_bf = (short*)(src_sorted + ((E + 63) / 64) * 64); // [M*128] bf16
    short* p_bf     = mean1_bf + (long)M * 128;                 // [M*128] bf16
    short* h_bf     = p_bf + (long)M * 128;                     // [M*256] bf16
    short* wbuf     = h_bf + (long)M * 256;                     // 8 x 32768 shorts
    const int WN = 256 * 128;
    short *W1l_hi = wbuf,          *W1l_lo = wbuf + WN;
    short *W1r_hi = wbuf + 2 * WN, *W1r_lo = wbuf + 3 * WN;
    short *W2l_hi = wbuf + 4 * WN, *W2l_lo = wbuf + 5 * WN;
    short *W2r_hi = wbuf + 6 * WN, *W2r_lo = wbuf + 7 * WN;
    short* x_bf     = wbuf + 8 * WN;                            // [M*128] bf16

    const int TB = 256;
    const int nbF  = (int)(((long)M * 128 / 8 + TB - 1) / TB); // f2bf blocks
    const int nbW  = 512;                          // 4 x 128 wsplit blocks
    const int nbC  = (E + 8191) / 8192;            // coarse-count blocks
    const int NMS  = (E + 4095) / 4096;            // msplit blocks

    hipMemsetAsync(ccount, 0, 256 * sizeof(int), stream);
    prep_kernel<<<dim3(nbF + nbW + nbC), dim3(TB), 0, stream>>>(
        x, x_bf, (long)M * 128, W1l, W1r, W2l, W2r, wbuf, WN, dst, ccount, E, nbF, nbW);
    ccscan_kernel<<<dim3(1), dim3(64), 0, stream>>>(ccount, cbase, gcur, NBK, E);
    msplit_kernel<<<dim3(NMS), dim3(1024), 0, stream>>>(src, dst, gcur, staging, E);
    bsort_kernel<<<dim3(NBK), dim3(1024), 0, stream>>>(staging, cbase, offs, src_sorted, M, NBK);

    const int MB = (M + 127) / 128;   // 391

    // layer 1
    agg_mean_kernel<128, true, false><<<dim3((M + 3) / 4), dim3(TB), 0, stream>>>(x_bf, src_sorted, offs, mean1_bf, M);
    mfma_gemm<128, 128, 256, true, true, true, true>
        <<<dim3(MB, 2), dim3(TB), 0, stream>>>(mean1_bf, x_bf, W1l_hi, W1l_lo, W1r_hi, W1r_lo,
                                               b1, h_bf, M);
    // layer 2: p = h@W2l^T (bf16), out = h@W2r^T + b2 (fp32), h staged once
    mfma_gemm_dual<256, 128>
        <<<dim3(MB), dim3(TB), 0, stream>>>(h_bf, W2l_hi, W2l_lo, W2r_hi, W2r_lo,
                                            b2, p_bf, out, M);
    // out += mean_agg(p)
    agg_mean_kernel<128, false, true><<<dim3((M + 3) / 4), dim3(TB), 0, stream>>>(p_bf, src_sorted, offs, out, M);
}

// Round 15
// 240.581 us; speedup vs baseline: 1.0148x; 1.0148x over previous
//
#include <hip/hip_runtime.h>

// ---------------------------------------------------------------------------
// 2-layer GraphSAGE (mean aggr), CSR-pull aggregation + bf16-MFMA GEMMs.
//   prep: x->bf16 + weight hi/lo split + COARSE (dst>>8) LDS histogram
//   ccscan: 1-block scan of 196 coarse counts -> cbase/gcur
//   msplit: block-local LDS sort by dst>>8, coalesced run flush -> staging
//   bsort: per-bucket fine hist -> offs[] + counting sort -> src_sorted
//   mean1 = mean_agg(x_bf)                      -> bf16   [M,128]
//   h     = relu(mean1@W1l^T + b1 + x_bf@W1r^T) -> bf16   [M,256]  (MFMA)
//   layer-2 GEMM, grid (MB,2): y=0 p=h@W2l^T (bf16), y=1 out0=h@W2r^T+b2 (fp32)
//     (was a fused dual kernel: 391 blocks, 51KB LDS, Occupancy 7%, MfmaUtil 11%
//      -> occupancy-starved at 41.7us; split doubles grid, 30.7KB LDS)
//   out  += mean_agg(p)
// Weights hi/lo bf16 split (2 MFMAs/product) — REQUIRED: single-bf16 weights
// measured absmax 6.3e-2 > 2.8e-2 (round 10); hi/lo gives 7.8e-3.
// Aggregation: dword-per-lane (lane owns 2 cols), 4x edge unroll — REQUIRED:
// the 2-edge/wave uint2 variant measured 4.35e-2 (rounds 10/12, unexplained).
// ws: ccount|cbase|gcur|offs | staging(uint2 E) | src_sorted[E]
//     | mean1_bf | p_bf | h_bf | wbuf(8xWN hi/lo) | x_bf   total ~74MB
// ---------------------------------------------------------------------------

typedef short bf16x8 __attribute__((ext_vector_type(8)));
typedef float f32x4  __attribute__((ext_vector_type(4)));

__device__ __forceinline__ unsigned f2bf(float f) {         // RNE fp32->bf16 bits
    unsigned u = __float_as_uint(f);
    return (u + 0x7FFFu + ((u >> 16) & 1u)) >> 16;
}
__device__ __forceinline__ unsigned pack2(float a, float b) {
    return f2bf(a) | (f2bf(b) << 16);
}
__device__ __forceinline__ float2 bfunpack(unsigned u) {    // (low, high) bf16 -> fp32
    return make_float2(__uint_as_float(u << 16), __uint_as_float(u & 0xffff0000u));
}

// exclusive scan of 256 ints in LDS (wave 0 only; caller syncs)
__device__ __forceinline__ void scan256(const int* __restrict__ h,
                                        int* __restrict__ out, int tid) {
    if (tid < 64) {
        const int i4 = tid * 4;
        const int v0 = h[i4], v1 = h[i4 + 1], v2 = h[i4 + 2], v3 = h[i4 + 3];
        const int t = v0 + v1 + v2 + v3;
        int x = t;
        #pragma unroll
        for (int dd = 1; dd < 64; dd <<= 1) {
            const int y = __shfl_up(x, dd, 64);
            if (tid >= dd) x += y;
        }
        const int ex = x - t;
        out[i4] = ex; out[i4 + 1] = ex + v0;
        out[i4 + 2] = ex + v0 + v1; out[i4 + 3] = ex + v0 + v1 + v2;
    }
}

// ----------------------------- fused prep ----------------------------------
// roles by blockIdx.x: [0,nbF) f2bf(x) | [nbF,nbF+nbW) wsplit | rest: coarse count
__global__ __launch_bounds__(256)
void prep_kernel(const float* __restrict__ x, short* __restrict__ x_bf, long nx,
                 const float* __restrict__ W0, const float* __restrict__ W1,
                 const float* __restrict__ W2, const float* __restrict__ W3,
                 short* __restrict__ wbuf, int wn,
                 const int* __restrict__ dst, int* __restrict__ ccount, int E,
                 int nbF, int nbW) {
    __shared__ int ch[256];
    const int bx = blockIdx.x, tid = threadIdx.x;
    if (bx < nbF) {
        const long i = ((long)bx * 256 + tid) * 8;
        if (i + 8 <= nx) {
            const float4 a = *(const float4*)(x + i);
            const float4 b = *(const float4*)(x + i + 4);
            *(uint4*)(x_bf + i) = make_uint4(pack2(a.x, a.y), pack2(a.z, a.w),
                                             pack2(b.x, b.y), pack2(b.z, b.w));
        }
    } else if (bx < nbF + nbW) {
        const int rel = bx - nbF;
        const int w = rel >> 7;                  // 128 blocks per weight
        const float* __restrict__ W = (w == 0) ? W0 : (w == 1) ? W1 : (w == 2) ? W2 : W3;
        short* hi = wbuf + (long)(2 * w) * wn;
        short* lo = hi + wn;
        const int i = (rel & 127) * 256 + tid;
        if (i < wn) {
            const float v = W[i];
            const unsigned h = f2bf(v);
            hi[i] = (short)h;
            lo[i] = (short)f2bf(v - __uint_as_float(h << 16));
        }
    } else {
        const int hb = bx - nbF - nbW;
        ch[tid] = 0;
        __syncthreads();
        const long base = (long)hb * 8192;
        #pragma unroll
        for (int k = 0; k < 32; ++k) {
            const long i = base + (long)k * 256 + tid;
            if (i < E) atomicAdd(&ch[dst[i] >> 8], 1);
        }
        __syncthreads();
        const int c = ch[tid];
        if (c) atomicAdd(&ccount[tid], c);
    }
}

// ----------------------------- coarse scan (1 block, 64 thr) ---------------
__global__ void ccscan_kernel(const int* __restrict__ ccount, int* __restrict__ cbase,
                              int* __restrict__ gcur, int NBK, int E) {
    const int lane = threadIdx.x;   // 64 threads
    int v[4]; int t = 0;
    #pragma unroll
    for (int i = 0; i < 4; ++i) {
        const int b = lane * 4 + i;
        v[i] = (b < NBK) ? ccount[b] : 0;
        t += v[i];
    }
    int x = t;
    #pragma unroll
    for (int d = 1; d < 64; d <<= 1) {
        const int y = __shfl_up(x, d, 64);
        if (lane >= d) x += y;
    }
    int ex = x - t;   // exclusive prefix of this thread's chunk
    #pragma unroll
    for (int i = 0; i < 4; ++i) {
        const int b = lane * 4 + i;
        if (b < NBK) { cbase[b] = ex; gcur[b] = ex; }
        ex += v[i];
    }
    if (lane == 63) cbase[NBK] = E;
}

// ----------------------------- coarse multisplit ---------------------------
__global__ __launch_bounds__(1024)
void msplit_kernel(const int* __restrict__ src, const int* __restrict__ dst,
                   int* __restrict__ gcur, uint2* __restrict__ staging, int E) {
    __shared__ int hist[256], scanex[256], gb[256];
    __shared__ uint2 pairs[4096];
    const int tid = threadIdx.x;
    const long base = (long)blockIdx.x * 4096;
    const int cnt = min(4096, (int)(E - base));
    if (tid < 256) hist[tid] = 0;
    __syncthreads();
    int d[4], s[4];
    #pragma unroll
    for (int k = 0; k < 4; ++k) {
        const int i = tid + k * 1024;
        if (i < cnt) {
            d[k] = dst[base + i]; s[k] = src[base + i];
            atomicAdd(&hist[d[k] >> 8], 1);
        }
    }
    __syncthreads();
    scan256(hist, scanex, tid);
    __syncthreads();
    if (tid < 256) {
        const int c = hist[tid];
        gb[tid] = c ? atomicAdd(&gcur[tid], c) : 0;
        hist[tid] = scanex[tid];                 // becomes LDS cursor
    }
    __syncthreads();
    #pragma unroll
    for (int k = 0; k < 4; ++k) {
        const int i = tid + k * 1024;
        if (i < cnt) {
            const int b = d[k] >> 8;
            const int pos = atomicAdd(&hist[b], 1);
            pairs[pos] = make_uint2((unsigned)s[k], (unsigned)d[k]);
        }
    }
    __syncthreads();
    #pragma unroll
    for (int k = 0; k < 4; ++k) {
        const int i = tid + k * 1024;
        if (i < cnt) {
            const uint2 pr = pairs[i];
            const int b = (int)(pr.y >> 8);
            staging[gb[b] + (i - scanex[b])] = pr;    // bucket-contiguous runs
        }
    }
}

// ----------------------------- per-bucket sort + offs ----------------------
__global__ __launch_bounds__(1024)
void bsort_kernel(const uint2* __restrict__ staging, const int* __restrict__ cbase,
                  int* __restrict__ offs, int* __restrict__ src_sorted,
                  int M, int NBK) {
    const int b = blockIdx.x;
    const int n0 = b * 256;
    const int s0 = cbase[b], s1 = cbase[b + 1];
    const int cnt = s1 - s0;
    const int tid = threadIdx.x;
    __shared__ int hist[256], base2[256];
    __shared__ int lsrc[8192];
    if (tid < 256) hist[tid] = 0;
    __syncthreads();
    for (int i = tid; i < cnt; i += 1024)
        atomicAdd(&hist[staging[s0 + i].y & 255], 1);
    __syncthreads();
    scan256(hist, base2, tid);
    __syncthreads();
    if (tid < 256) {
        const int node = n0 + tid;
        if (node < M) offs[node] = s0 + base2[tid];
        hist[tid] = base2[tid];                  // becomes cursor
    }
    if (b == NBK - 1 && tid == 0) offs[M] = s1;
    __syncthreads();
    if (cnt <= 8192) {
        for (int i = tid; i < cnt; i += 1024) {
            const uint2 pr = staging[s0 + i];
            const int pos = atomicAdd(&hist[pr.y & 255], 1);
            lsrc[pos] = (int)pr.x;
        }
        __syncthreads();
        for (int i = tid; i < cnt; i += 1024)
            src_sorted[s0 + i] = lsrc[i];        // fully coalesced
    } else {                                     // rare huge-bucket fallback
        for (int i = tid; i < cnt; i += 1024) {
            const uint2 pr = staging[s0 + i];
            const int pos = atomicAdd(&hist[pr.y & 255], 1);
            src_sorted[s0 + pos] = (int)pr.x;
        }
    }
}

// ----------------------------- aggregation ---------------------------------
template<int F, bool BF16_OUT, bool ADD>
__global__ __launch_bounds__(256)
void agg_mean_kernel(const short* __restrict__ feat, const int* __restrict__ src_sorted,
                     const int* __restrict__ offs, void* __restrict__ outv, int M) {
    const int node = blockIdx.x * 4 + (threadIdx.x >> 6);
    if (node >= M) return;
    const int lane = threadIdx.x & 63;
    const int start = offs[node], end = offs[node + 1];
    const unsigned* fb = (const unsigned*)feat;       // row stride F/2 dwords
    float2 acc = make_float2(0.f, 0.f);
    for (int e0 = start; e0 < end; e0 += 64) {
        const int n = min(64, end - e0);
        const int sv = (e0 + lane < end) ? src_sorted[e0 + lane] : 0;
        int j = 0;
        for (; j + 4 <= n; j += 4) {
            const int s0 = __shfl(sv, j, 64),     s1 = __shfl(sv, j + 1, 64);
            const int s2 = __shfl(sv, j + 2, 64), s3 = __shfl(sv, j + 3, 64);
            const unsigned u0 = fb[(long)s0 * (F / 2) + lane];
            const unsigned u1 = fb[(long)s1 * (F / 2) + lane];
            const unsigned u2 = fb[(long)s2 * (F / 2) + lane];
            const unsigned u3 = fb[(long)s3 * (F / 2) + lane];
            const float2 v0 = bfunpack(u0), v1 = bfunpack(u1);
            const float2 v2 = bfunpack(u2), v3 = bfunpack(u3);
            acc.x += (v0.x + v1.x) + (v2.x + v3.x);
            acc.y += (v0.y + v1.y) + (v2.y + v3.y);
        }
        for (; j < n; ++j) {
            const int s = __shfl(sv, j, 64);
            const float2 v = bfunpack(fb[(long)s * (F / 2) + lane]);
            acc.x += v.x; acc.y += v.y;
        }
    }
    const float inv = (end > start) ? 1.0f / (float)(end - start) : 0.f;
    acc.x *= inv; acc.y *= inv;
    if (BF16_OUT) {
        ((unsigned*)outv)[(long)node * (F / 2) + lane] = pack2(acc.x, acc.y);
    } else if (ADD) {
        float2* op = reinterpret_cast<float2*>((float*)outv + (long)node * F + lane * 2);
        const float2 cur = *op;
        *op = make_float2(cur.x + acc.x, cur.y + acc.y);
    } else {
        *reinterpret_cast<float2*>((float*)outv + (long)node * F + lane * 2) = acc;
    }
}

// ----------------------------- MFMA GEMM phase -----------------------------
// C[M][NOUT] tile 128x128, 4 waves (2x2), 16x16x32 bf16 MFMA, fp32 acc.
// A: [M][KP] bf16.  W hi/lo: [NOUT][KP] each. Product a*bhi + a*blo.
template<int KP>
__device__ __forceinline__ void gemm_phase(const short* __restrict__ A,
    const short* __restrict__ Whi, const short* __restrict__ Wlo,
    int M, int row0, int col0,
    short (*As)[40], short (*Bh)[40], short (*Bl)[40], f32x4 (&acc)[4][4])
{
    const int tid = threadIdx.x;
    const int lane = tid & 63;
    const int wr = (tid >> 7) & 1, wc = (tid >> 6) & 1;
    const int l15 = lane & 15, l4 = lane >> 4;
    const int sr = tid >> 1;
    const int sk = (tid & 1) * 16;
    const int gr = row0 + sr;

    for (int k0 = 0; k0 < KP; k0 += 32) {
        {
            const short* ap = A + (long)gr * KP + k0 + sk;
            uint4 v0 = make_uint4(0, 0, 0, 0), v1 = make_uint4(0, 0, 0, 0);
            if (gr < M) { v0 = *(const uint4*)ap; v1 = *(const uint4*)(ap + 8); }
            *(uint4*)&As[sr][sk]     = v0;
            *(uint4*)&As[sr][sk + 8] = v1;
        }
        {
            const short* bh = Whi + (long)(col0 + sr) * KP + k0 + sk;
            const short* bl = Wlo + (long)(col0 + sr) * KP + k0 + sk;
            *(uint4*)&Bh[sr][sk]     = *(const uint4*)bh;
            *(uint4*)&Bh[sr][sk + 8] = *(const uint4*)(bh + 8);
            *(uint4*)&Bl[sr][sk]     = *(const uint4*)bl;
            *(uint4*)&Bl[sr][sk + 8] = *(const uint4*)(bl + 8);
        }
        __syncthreads();
        bf16x8 bhf[4], blf[4];
        #pragma unroll
        for (int n = 0; n < 4; ++n) {
            const int br = wc * 64 + n * 16 + l15;
            bhf[n] = *(const bf16x8*)&Bh[br][l4 * 8];
            blf[n] = *(const bf16x8*)&Bl[br][l4 * 8];
        }
        #pragma unroll
        for (int m = 0; m < 4; ++m) {
            const bf16x8 af = *(const bf16x8*)&As[wr * 64 + m * 16 + l15][l4 * 8];
            #pragma unroll
            for (int n = 0; n < 4; ++n) {
                acc[m][n] = __builtin_amdgcn_mfma_f32_16x16x32_bf16(af, bhf[n], acc[m][n], 0, 0, 0);
                acc[m][n] = __builtin_amdgcn_mfma_f32_16x16x32_bf16(af, blf[n], acc[m][n], 0, 0, 0);
            }
        }
        __syncthreads();
    }
}

// ----------------------------- MFMA GEMM (layer 1) -------------------------
template<int K1, int K2, int NOUT, bool TWO_PHASE,
         bool RELU, bool HAS_BIAS, bool OUT_BF16>
__global__ __launch_bounds__(256)
void mfma_gemm(const short* __restrict__ A1, const short* __restrict__ A2,
               const short* __restrict__ B1hi, const short* __restrict__ B1lo,
               const short* __restrict__ B2hi, const short* __restrict__ B2lo,
               const float* __restrict__ bias, void* __restrict__ Cv, int M)
{
    __shared__ __align__(16) short As[128][40];
    __shared__ __align__(16) short Bh[128][40];
    __shared__ __align__(16) short Bl[128][40];
    const int row0 = blockIdx.x * 128, col0 = blockIdx.y * 128;
    f32x4 acc[4][4] = {};

    if constexpr (TWO_PHASE)
        gemm_phase<K1>(A1, B1hi, B1lo, M, row0, col0, As, Bh, Bl, acc);
    gemm_phase<K2>(A2, B2hi, B2lo, M, row0, col0, As, Bh, Bl, acc);

    const int tid = threadIdx.x, lane = tid & 63;
    const int wr = (tid >> 7) & 1, wc = (tid >> 6) & 1;
    const int l15 = lane & 15, l4 = lane >> 4;
    float bv[4];
    #pragma unroll
    for (int n = 0; n < 4; ++n)
        bv[n] = HAS_BIAS ? bias[col0 + wc * 64 + n * 16 + l15] : 0.f;
    #pragma unroll
    for (int m = 0; m < 4; ++m) {
        #pragma unroll
        for (int i = 0; i < 4; ++i) {
            const int r = row0 + wr * 64 + m * 16 + l4 * 4 + i;
            if (r < M) {
                #pragma unroll
                for (int n = 0; n < 4; ++n) {
                    const int c = col0 + wc * 64 + n * 16 + l15;
                    float v = acc[m][n][i] + bv[n];
                    if (RELU) v = fmaxf(v, 0.f);
                    if (OUT_BF16) ((short*)Cv)[(long)r * NOUT + c] = (short)f2bf(v);
                    else          ((float*)Cv)[(long)r * NOUT + c] = v;
                }
            }
        }
    }
}

// ----------------------------- split layer-2 GEMM --------------------------
// grid (MB, 2): y=0 -> Ca = A@Wa^T (bf16, no bias); y=1 -> Cb = A@Wb^T + bias (fp32)
template<int K, int NOUT>
__global__ __launch_bounds__(256)
void mfma_gemm_split(const short* __restrict__ A,
                     const short* __restrict__ Wahi, const short* __restrict__ Walo,
                     const short* __restrict__ Wbhi, const short* __restrict__ Wblo,
                     const float* __restrict__ bias, short* __restrict__ Ca,
                     float* __restrict__ Cb, int M)
{
    __shared__ __align__(16) short As[128][40];
    __shared__ __align__(16) short Bh[128][40];
    __shared__ __align__(16) short Bl[128][40];
    const int row0 = blockIdx.x * 128;
    const bool second = (blockIdx.y != 0);
    const short* __restrict__ Whi = second ? Wbhi : Wahi;
    const short* __restrict__ Wlo = second ? Wblo : Walo;
    f32x4 acc[4][4] = {};

    gemm_phase<K>(A, Whi, Wlo, M, row0, 0, As, Bh, Bl, acc);

    const int tid = threadIdx.x, lane = tid & 63;
    const int wr = (tid >> 7) & 1, wc = (tid >> 6) & 1;
    const int l15 = lane & 15, l4 = lane >> 4;
    float bv[4];
    #pragma unroll
    for (int n = 0; n < 4; ++n)
        bv[n] = second ? bias[wc * 64 + n * 16 + l15] : 0.f;
    #pragma unroll
    for (int m = 0; m < 4; ++m) {
        #pragma unroll
        for (int i = 0; i < 4; ++i) {
            const int r = row0 + wr * 64 + m * 16 + l4 * 4 + i;
            if (r < M) {
                #pragma unroll
                for (int n = 0; n < 4; ++n) {
                    const int c = wc * 64 + n * 16 + l15;
                    if (!second) Ca[(long)r * NOUT + c] = (short)f2bf(acc[m][n][i]);
                    else         Cb[(long)r * NOUT + c] = acc[m][n][i] + bv[n];
                }
            }
        }
    }
}

// ----------------------------- launch --------------------------------------
extern "C" void kernel_launch(void* const* d_in, const int* in_sizes, int n_in,
                              void* d_out, int out_size, void* d_ws, size_t ws_size,
                              hipStream_t stream) {
    const float* x   = (const float*)d_in[0];
    const int*   ei  = (const int*)d_in[1];
    const float* W1l = (const float*)d_in[2];
    const float* b1  = (const float*)d_in[3];
    const float* W1r = (const float*)d_in[4];
    const float* W2l = (const float*)d_in[5];
    const float* b2  = (const float*)d_in[6];
    const float* W2r = (const float*)d_in[7];
    float* out = (float*)d_out;

    const int M = in_sizes[0] / 128;   // 50000
    const int E = in_sizes[1] / 2;     // 800000
    const int* src = ei;
    const int* dst = ei + E;

    const int NBK = (M + 255) / 256;               // 196 coarse buckets
    const int Mal = ((M + 1 + 63) / 64) * 64;

    int* ccount     = (int*)d_ws;                               // [256]
    int* cbase      = ccount + 256;                             // [NBK+1] (<=320)
    int* gcur       = cbase + 320;                              // [256]
    int* offs       = gcur + 256;                               // [M+1]
    uint2* staging  = (uint2*)(offs + Mal);                     // [E] 8B pairs
    int* src_sorted = (int*)(staging + E);                      // [E]
    short* mean1_bf = (short*)(src_sorted + ((E + 63) / 64) * 64); // [M*128] bf16
    short* p_bf     = mean1_bf + (long)M * 128;                 // [M*128] bf16
    short* h_bf     = p_bf + (long)M * 128;                     // [M*256] bf16
    short* wbuf     = h_bf + (long)M * 256;                     // 8 x 32768 shorts
    const int WN = 256 * 128;
    short *W1l_hi = wbuf,          *W1l_lo = wbuf + WN;
    short *W1r_hi = wbuf + 2 * WN, *W1r_lo = wbuf + 3 * WN;
    short *W2l_hi = wbuf + 4 * WN, *W2l_lo = wbuf + 5 * WN;
    short *W2r_hi = wbuf + 6 * WN, *W2r_lo = wbuf + 7 * WN;
    short* x_bf     = wbuf + 8 * WN;                            // [M*128] bf16

    const int TB = 256;
    const int nbF  = (int)(((long)M * 128 / 8 + TB - 1) / TB); // f2bf blocks
    const int nbW  = 512;                          // 4 x 128 wsplit blocks
    const int nbC  = (E + 8191) / 8192;            // coarse-count blocks
    const int NMS  = (E + 4095) / 4096;            // msplit blocks

    hipMemsetAsync(ccount, 0, 256 * sizeof(int), stream);
    prep_kernel<<<dim3(nbF + nbW + nbC), dim3(TB), 0, stream>>>(
        x, x_bf, (long)M * 128, W1l, W1r, W2l, W2r, wbuf, WN, dst, ccount, E, nbF, nbW);
    ccscan_kernel<<<dim3(1), dim3(64), 0, stream>>>(ccount, cbase, gcur, NBK, E);
    msplit_kernel<<<dim3(NMS), dim3(1024), 0, stream>>>(src, dst, gcur, staging, E);
    bsort_kernel<<<dim3(NBK), dim3(1024), 0, stream>>>(staging, cbase, offs, src_sorted, M, NBK);

    const int MB = (M + 127) / 128;   // 391

    // layer 1
    agg_mean_kernel<128, true, false><<<dim3((M + 3) / 4), dim3(TB), 0, stream>>>(x_bf, src_sorted, offs, mean1_bf, M);
    mfma_gemm<128, 128, 256, true, true, true, true>
        <<<dim3(MB, 2), dim3(TB), 0, stream>>>(mean1_bf, x_bf, W1l_hi, W1l_lo, W1r_hi, W1r_lo,
                                               b1, h_bf, M);
    // layer 2 (split over grid.y): p = h@W2l^T (bf16), out = h@W2r^T + b2 (fp32)
    mfma_gemm_split<256, 128>
        <<<dim3(MB, 2), dim3(TB), 0, stream>>>(h_bf, W2l_hi, W2l_lo, W2r_hi, W2r_lo,
                                               b2, p_bf, out, M);
    // out += mean_agg(p)
    agg_mean_kernel<128, false, true><<<dim3((M + 3) / 4), dim3(TB), 0, stream>>>(p_bf, src_sorted, offs, out, M);
}